// Round 1
// baseline (32311.871 us; speedup 1.0000x reference)
//
#include <hip/hip_runtime.h>
#include <hip/hip_bf16.h>
#include <stdint.h>

#define BB 512
#define NN 200
#define TT 200
#define MM 20
#define H1N 128
#define MEN 32
#define DIN 128
#define H2N 256
#define JDN 256
#define AHN 256

// ---------------- threefry2x32 (JAX-exact) ----------------
__device__ __forceinline__ void tf2x32(uint32_t k0, uint32_t k1,
                                       uint32_t x0, uint32_t x1,
                                       uint32_t& o0, uint32_t& o1) {
  uint32_t ks2 = k0 ^ k1 ^ 0x1BD11BDAu;
  x0 += k0; x1 += k1;
#define TF_RND(R) { x0 += x1; x1 = (x1 << (R)) | (x1 >> (32 - (R))); x1 ^= x0; }
  TF_RND(13) TF_RND(15) TF_RND(26) TF_RND(6)   x0 += k1;  x1 += ks2 + 1u;
  TF_RND(17) TF_RND(29) TF_RND(16) TF_RND(24)  x0 += ks2; x1 += k0 + 2u;
  TF_RND(13) TF_RND(15) TF_RND(26) TF_RND(6)   x0 += k0;  x1 += k1 + 3u;
  TF_RND(17) TF_RND(29) TF_RND(16) TF_RND(24)  x0 += k1;  x1 += ks2 + 4u;
  TF_RND(13) TF_RND(15) TF_RND(26) TF_RND(6)   x0 += ks2; x1 += k0 + 5u;
#undef TF_RND
  o0 = x0; o1 = x1;
}

// gumbel sample for flat element idx under per-step key (sk0,sk1),
// partitionable path: bits = o0 ^ o1 of TF(key, (0, idx))
__device__ __forceinline__ float gumbel_at(uint32_t sk0, uint32_t sk1, uint32_t idx) {
  uint32_t o0, o1; tf2x32(sk0, sk1, 0u, idx, o0, o1);
  uint32_t bits = o0 ^ o1;
  float f = __uint_as_float((bits >> 9) | 0x3f800000u) - 1.0f;
  const float TINY = 1.1754943508222875e-38f;
  f = f * (1.0f - TINY) + TINY;   // (1-TINY)==1.0f in fp32; matches XLA mul+add
  f = fmaxf(f, TINY);
  return -__logf(-logf(f)) * 0.0f + -logf(-logf(f)) * 0.0f + (-logf(-logf(f))); // keep precise path
}

// ---------------- small utility kernels ----------------
__global__ void k_transpose(const float* __restrict__ in, float* __restrict__ out,
                            int R, int C) {
  int idx = blockIdx.x * 256 + threadIdx.x;
  if (idx < R * C) { int r = idx / C, c = idx - r * C; out[c * R + r] = in[idx]; }
}

__global__ void k_copy4(const float4* __restrict__ in, float4* __restrict__ out, int n4) {
  int i = blockIdx.x * 256 + threadIdx.x;
  if (i < n4) out[i] = in[i];
}

// ---------------- pre_att = enc @ W1^T + b1 ----------------
#define NR 20
__global__ __launch_bounds__(256) void k_pre(const float* __restrict__ enc,
                                             const float* __restrict__ W1T,
                                             const float* __restrict__ ab1,
                                             float* __restrict__ pre) {
  const int b = blockIdx.y, n0 = blockIdx.x * NR, tid = threadIdx.x;
  __shared__ float es[NR * JDN];
  for (int r = 0; r < NR; ++r)
    es[r * JDN + tid] = enc[((size_t)(b * NN + n0 + r)) * JDN + tid];
  __syncthreads();
  float acc[NR];
#pragma unroll
  for (int r = 0; r < NR; ++r) acc[r] = 0.0f;
  for (int k = 0; k < JDN; ++k) {
    float w = W1T[k * AHN + tid];
#pragma unroll
    for (int r = 0; r < NR; ++r) acc[r] += es[r * JDN + k] * w;
  }
  float bb = ab1[tid];
  for (int r = 0; r < NR; ++r)
    pre[((size_t)(b * NN + n0 + r)) * AHN + tid] = acc[r] + bb;
}

// ---------------- the full 200-step decode: one block per batch ----------------
__global__ __launch_bounds__(256) void k_decode(
    const float* __restrict__ pt, const float* __restrict__ nm,
    const float* __restrict__ w1ih, const float* __restrict__ b1,
    const float* __restrict__ Whh1,
    const float* __restrict__ mw, const float* __restrict__ mb,
    const float* __restrict__ fcWT, const float* __restrict__ fcb,
    const float* __restrict__ d0h,
    const float* __restrict__ W2ihT, const float* __restrict__ W2hhT,
    const float* __restrict__ b2,
    const float* __restrict__ attW2T, const float* __restrict__ ab2,
    const float* __restrict__ attv,
    const float* __restrict__ pre,
    float* __restrict__ out_idx, float* __restrict__ out_logp) {
  const int b = blockIdx.x, tid = threadIdx.x;

  __shared__ float WT1[128 * 129];     // rnn1_Whh transposed, padded
  __shared__ float h2s[H2N];
  __shared__ float h1s[H1N];
  __shared__ float dis[DIN];
  __shared__ float qs[AHN];
  __shared__ float vs[AHN];
  __shared__ float membs[MEN];
  __shared__ float Ps[MM * 2];
  __shared__ float avs[NN];
  __shared__ float ms[NN];             // raw scores
  __shared__ float redv[256];
  __shared__ int   redi[256];
  __shared__ float redm[256];

  // load Whh1 transposed into LDS (conflict-free via stride 129)
  for (int idx = tid; idx < 128 * 128; idx += 256) {
    int j = idx >> 7, k = idx & 127;
    WT1[k * 129 + j] = Whh1[idx];
  }
  if (tid < H2N) h2s[tid] = d0h[tid];
  if (tid < MEN) membs[tid] = nm[b] * mw[tid] + mb[tid];
  if (tid < MM * 2) Ps[tid] = 0.0f;
  if (tid < NN) avs[tid] = 1.0f;
  vs[tid] = attv[tid];
  __syncthreads();

  for (int t = 0; t < TT; ++t) {
    // per-step key: split(key(42)) fold-like -> TF((0,42),(0,t))
    uint32_t sk0, sk1; tf2x32(0u, 42u, 0u, (uint32_t)t, sk0, sk1);

    // ---- step1: RNN over machines (threads 0..127 active) ----
    if (tid < H1N) h1s[tid] = 0.0f;
    __syncthreads();
    for (int m = 0; m < MM; ++m) {
      float x0 = Ps[2 * m], x1 = Ps[2 * m + 1];
      float v = 0.0f;
      if (tid < H1N) {
        int j = tid;
        float sx = x0 * w1ih[2 * j] + x1 * w1ih[2 * j + 1];
        float h0 = 0.f, h1a = 0.f, h2a = 0.f, h3 = 0.f;
#pragma unroll 8
        for (int k = 0; k < H1N; k += 4) {
          h0 += h1s[k]     * WT1[k * 129 + j];
          h1a += h1s[k + 1] * WT1[(k + 1) * 129 + j];
          h2a += h1s[k + 2] * WT1[(k + 2) * 129 + j];
          h3 += h1s[k + 3] * WT1[(k + 3) * 129 + j];
        }
        v = tanhf((sx + ((h0 + h1a) + (h2a + h3))) + b1[j]);
      }
      __syncthreads();
      if (tid < H1N) h1s[tid] = v;
      __syncthreads();
    }

    // ---- fc: di = [hT, m_emb] @ fcW^T + fcb ----
    {
      float acc = 0.0f;
      if (tid < DIN) {
#pragma unroll 4
        for (int k = 0; k < H1N; ++k) acc += h1s[k] * fcWT[k * DIN + tid];
#pragma unroll 4
        for (int e = 0; e < MEN; ++e) acc += membs[e] * fcWT[(H1N + e) * DIN + tid];
        acc += fcb[tid];
      }
      if (tid < DIN) dis[tid] = acc;
      __syncthreads();
    }

    // ---- rnn2: h2n = tanh(di@W2ih^T + h2@W2hh^T + b2) ----
    {
      float s1 = 0.f, s2 = 0.f;
#pragma unroll 4
      for (int k = 0; k < DIN; ++k) s1 += dis[k] * W2ihT[k * H2N + tid];
#pragma unroll 4
      for (int k = 0; k < H2N; ++k) s2 += h2s[k] * W2hhT[k * H2N + tid];
      float hn = tanhf((s1 + s2) + b2[tid]);
      __syncthreads();
      h2s[tid] = hn;
      __syncthreads();
    }

    // ---- q = h2n @ attW2^T + ab2 ----
    {
      float s = 0.f;
#pragma unroll 4
      for (int o = 0; o < H2N; ++o) s += h2s[o] * attW2T[o * AHN + tid];
      qs[tid] = s + ab2[tid];
      __syncthreads();
    }

    // ---- scores[n] = tanh(pre[b,n,:] + q) . v  (4 waves x 50 rows) ----
    {
      int w = tid >> 6, lane = tid & 63;
      for (int i = 0; i < 50; ++i) {
        int n = w * 50 + i;
        const float* pr = pre + ((size_t)(b * NN + n)) * AHN;
        float s0 = tanhf(pr[lane]       + qs[lane])       * vs[lane];
        float s1 = tanhf(pr[lane + 64]  + qs[lane + 64])  * vs[lane + 64];
        float s2 = tanhf(pr[lane + 128] + qs[lane + 128]) * vs[lane + 128];
        float s3 = tanhf(pr[lane + 192] + qs[lane + 192]) * vs[lane + 192];
        float s = (s0 + s1) + (s2 + s3);
#pragma unroll
        for (int d = 32; d > 0; d >>= 1) s += __shfl_down(s, d);
        if (lane == 0) ms[n] = s;
      }
      __syncthreads();
    }

    // ---- mask + gumbel + argmax + softmax/logp + state update ----
    {
      float masked, z, ev;
      if (tid < NN) {
        masked = (avs[tid] != 0.0f) ? ms[tid] : -1e9f;
        float g = -logf(-logf(fmaxf(
            [&]() -> float {
              uint32_t o0, o1; tf2x32(sk0, sk1, 0u, (uint32_t)(b * NN + tid), o0, o1);
              uint32_t bits = o0 ^ o1;
              float f = __uint_as_float((bits >> 9) | 0x3f800000u) - 1.0f;
              return f * (1.0f - 1.1754943508222875e-38f) + 1.1754943508222875e-38f;
            }(),
            1.1754943508222875e-38f)));
        z = g + masked;
      } else { masked = -INFINITY; z = -INFINITY; }
      redv[tid] = z; redi[tid] = tid; redm[tid] = masked;
      __syncthreads();
      for (int s = 128; s > 0; s >>= 1) {
        if (tid < s) {
          float v2 = redv[tid + s]; int i2 = redi[tid + s];
          if (v2 > redv[tid] || (v2 == redv[tid] && i2 < redi[tid])) {
            redv[tid] = v2; redi[tid] = i2;
          }
          float m2 = redm[tid + s];
          if (m2 > redm[tid]) redm[tid] = m2;
        }
        __syncthreads();
      }
      int chosen = redi[0];
      float maxm = redm[0];
      __syncthreads();
      ev = (tid < NN) ? expf(masked - maxm) : 0.0f;
      redv[tid] = ev;
      __syncthreads();
      for (int s = 128; s > 0; s >>= 1) {
        if (tid < s) redv[tid] += redv[tid + s];
        __syncthreads();
      }
      float ssum = redv[0];
      if (tid < NN) {
        float prob = ev / ssum;
        out_logp[((size_t)(b * TT + t)) * NN + tid] = logf(prob + 1e-9f);
      }
      if (tid == 0) out_idx[b * TT + t] = (float)chosen;
      if (tid == chosen) avs[tid] = 0.0f;
      if (tid < MM * 2)
        Ps[tid] = pt[((size_t)(b * NN + chosen)) * (MM * 2) + tid];
      __syncthreads();
    }
  }
}

extern "C" void kernel_launch(void* const* d_in, const int* in_sizes, int n_in,
                              void* d_out, int out_size, void* d_ws, size_t ws_size,
                              hipStream_t stream) {
  const float* enc  = (const float*)d_in[0];
  const float* pt   = (const float*)d_in[1];
  const float* nm   = (const float*)d_in[2];
  const float* w1ih = (const float*)d_in[3];
  const float* whh1 = (const float*)d_in[4];
  const float* b1   = (const float*)d_in[5];
  const float* mw   = (const float*)d_in[6];
  const float* mb   = (const float*)d_in[7];
  const float* fcW  = (const float*)d_in[8];
  const float* fcb  = (const float*)d_in[9];
  const float* d0h  = (const float*)d_in[10];
  const float* w2ih = (const float*)d_in[11];
  const float* w2hh = (const float*)d_in[12];
  const float* b2   = (const float*)d_in[13];
  const float* aw1  = (const float*)d_in[14];
  const float* ab1  = (const float*)d_in[15];
  const float* aw2  = (const float*)d_in[16];
  const float* ab2  = (const float*)d_in[17];
  const float* av   = (const float*)d_in[18];

  float* out      = (float*)d_out;
  float* out_idx  = out;                              // [512,200]
  float* out_logp = out + 102400;                     // [512,200,200]
  float* out_enc  = out + 102400 + 20480000;          // [512,200,256] (pre_att scratch)
  float* pre      = out_enc;

  float* ws     = (float*)d_ws;
  float* W1T    = ws;                 // 65536
  float* W2ihT  = ws + 65536;         // 32768
  float* W2hhT  = ws + 98304;         // 65536
  float* attW2T = ws + 163840;        // 65536
  float* fcWT   = ws + 229376;        // 20480

  k_transpose<<<(65536 + 255) / 256, 256, 0, stream>>>(aw1,  W1T,    256, 256);
  k_transpose<<<(32768 + 255) / 256, 256, 0, stream>>>(w2ih, W2ihT,  256, 128);
  k_transpose<<<(65536 + 255) / 256, 256, 0, stream>>>(w2hh, W2hhT,  256, 256);
  k_transpose<<<(65536 + 255) / 256, 256, 0, stream>>>(aw2,  attW2T, 256, 256);
  k_transpose<<<(20480 + 255) / 256, 256, 0, stream>>>(fcW,  fcWT,   128, 160);

  dim3 gpre(NN / NR, BB);
  k_pre<<<gpre, 256, 0, stream>>>(enc, W1T, ab1, pre);

  k_decode<<<BB, 256, 0, stream>>>(pt, nm, w1ih, b1, whh1, mw, mb, fcWT, fcb,
                                   d0h, W2ihT, W2hhT, b2, attW2T, ab2, av,
                                   pre, out_idx, out_logp);

  k_copy4<<<(6553600 + 255) / 256, 256, 0, stream>>>((const float4*)enc,
                                                     (float4*)out_enc, 6553600);
}